// Round 1
// baseline (177.649 us; speedup 1.0000x reference)
//
#include <hip/hip_runtime.h>
#include <math.h>

#define NP 512
#define NBLK 512
#define NTHREADS 1024
#define NA_ 32
#define NCn 3
#define NG 36
#define NBT 40
#define NTAB 40

struct F3 { float x, y, z; };
__device__ inline F3 f3sub(F3 a, F3 b) { return {a.x - b.x, a.y - b.y, a.z - b.z}; }
__device__ inline F3 f3cross(F3 a, F3 b) {
    return {a.y * b.z - a.z * b.y, a.z * b.x - a.x * b.z, a.x * b.y - a.y * b.x};
}
__device__ inline float f3dot(F3 a, F3 b) { return a.x * b.x + a.y * b.y + a.z * b.z; }

// thread = (residue, torsion) with WAVE-UNIFORM torsion split (t = tid>>9):
// conn-path branch executes once per wave at full lane utilization instead of
// twice at half utilization. Partner angle exchanged via LDS (float2 read).
// Block-invariant tables (tor/down/rama_table/is_pro/upper_conn/table_params)
// are read directly from global (L1-resident, shared by all 512 blocks)
// instead of being re-staged into LDS by every block.
__global__ __launch_bounds__(NTHREADS, 8) void rama_kernel(
    const float* __restrict__ coords,        // (P, NB*NA, 3)
    const int*   __restrict__ offsets,       // (P, NB)
    const int*   __restrict__ block_type,    // (P, NB)
    const int*   __restrict__ inter,         // (P, NB, NC, 2)
    const int*   __restrict__ down,          // (NBT, NC, NA)
    const int*   __restrict__ bt_rama_table, // (NBT, 2)
    const int*   __restrict__ bt_upper_conn, // (NBT,)
    const int*   __restrict__ bt_is_pro,     // (NBT,)
    const int*   __restrict__ tor_atoms,     // (NBT, 8, 3)
    const float* __restrict__ rama_tables,   // (NTAB, G, G)
    const float* __restrict__ table_params,  // (NTAB, 2, 2)
    float*       __restrict__ out)           // (P,)
{
    __shared__ __align__(16) int   s_bt[NBLK];
    __shared__ __align__(16) int   s_off[NBLK];
    __shared__ __align__(16) int   s_inter[NBLK * NCn * 2];
    __shared__ __align__(16) float s_ang[NBLK * 2];
    __shared__ float partial[NTHREADS / 64];

    const int p   = blockIdx.x;
    const int tid = threadIdx.x;

    // ---- per-pose metadata (16 KB = 4096 ints = 1024 int4): one int4
    //      load + one ds_write_b128 per thread, fully coalesced ----
    {
        const int4* gi = (const int4*)(inter      + (size_t)p * NBLK * NCn * 2);
        const int4* gb = (const int4*)(block_type + (size_t)p * NBLK);
        const int4* go = (const int4*)(offsets    + (size_t)p * NBLK);
        if (tid < 768)      ((int4*)s_inter)[tid]     = gi[tid];
        else if (tid < 896) ((int4*)s_bt)[tid - 768]  = gb[tid - 768];
        else                ((int4*)s_off)[tid - 896] = go[tid - 896];
    }
    __syncthreads();

    const int b = tid & (NBLK - 1);   // residue
    const int t = tid >> 9;           // torsion (wave-uniform!)
    const int bt    = s_bt[b];
    const int off_b = s_off[b];
    const float* pose_coords = coords + (size_t)p * NBLK * NA_ * 3;

    // ---- 12 tor ints for this (bt, torsion): contiguous, 48B-aligned ->
    //      3x dwordx4 straight from the L1-resident 3.75 KB table ----
    const int4* tq = (const int4*)tor_atoms + (6 * bt + 3 * t);
    const int4 w0 = tq[0], w1 = tq[1], w2 = tq[2];
    const int ai[4]  = {w0.x, w0.w, w1.z, w2.y};
    const int ci[4]  = {w0.y, w1.x, w1.w, w2.z};
    const int nbd[4] = {w0.z, w1.y, w2.x, w2.w};

    // ---- resolve 4 atom indices ----
    int  g[4];
    bool ok4 = true;
    #pragma unroll
    for (int a = 0; a < 4; ++a) {
        if (ai[a] >= 0) {
            g[a] = off_b + ai[a];
        } else {
            const int sc = ci[a] > 0 ? ci[a] : 0;
            const int ib = (b * NCn + sc) * 2;
            const int ob = s_inter[ib + 0];
            const int oc = s_inter[ib + 1];
            ok4 = ok4 && (ci[a] >= 0) && (ob >= 0);
            const int obc = ob > 0 ? ob : 0;
            const int occ = oc > 0 ? oc : 0;
            const int obt = s_bt[obc];
            // 15 KB table, L2/L1-resident: direct load beats re-staging
            g[a] = s_off[obc] + down[(obt * NCn + occ) * NA_ + nbd[a]];
        }
    }

    // ---- coord gather: vector fast path for a contiguous aligned triple
    //      (the 3 local atoms 0..2 of the residue), scalar otherwise ----
    F3 pts[4];
    bool done = false;
    if (g[2] == g[1] + 1 && g[3] == g[2] + 1 && (g[1] & 3) == 0) {
        const float* base = pose_coords + (size_t)g[1] * 3;
        const float4 q0 = ((const float4*)base)[0];
        const float4 q1 = ((const float4*)base)[1];
        const float  q2 = base[8];
        pts[1] = {q0.x, q0.y, q0.z};
        pts[2] = {q0.w, q1.x, q1.y};
        pts[3] = {q1.z, q1.w, q2};
        const float* c0 = pose_coords + (size_t)g[0] * 3;
        pts[0] = {c0[0], c0[1], c0[2]};
        done = true;
    } else if (g[1] == g[0] + 1 && g[2] == g[1] + 1 && (g[0] & 3) == 0) {
        const float* base = pose_coords + (size_t)g[0] * 3;
        const float4 q0 = ((const float4*)base)[0];
        const float4 q1 = ((const float4*)base)[1];
        const float  q2 = base[8];
        pts[0] = {q0.x, q0.y, q0.z};
        pts[1] = {q0.w, q1.x, q1.y};
        pts[2] = {q1.z, q1.w, q2};
        const float* c3 = pose_coords + (size_t)g[3] * 3;
        pts[3] = {c3[0], c3[1], c3[2]};
        done = true;
    }
    if (!done) {
        #pragma unroll
        for (int a = 0; a < 4; ++a) {
            const float* c = pose_coords + (size_t)g[a] * 3;
            pts[a] = {c[0], c[1], c[2]};
        }
    }

    // ---- dihedral ----
    const F3 d1 = f3sub(pts[1], pts[0]);
    const F3 d2 = f3sub(pts[2], pts[1]);
    const F3 d3 = f3sub(pts[3], pts[2]);
    const F3 n1 = f3cross(d1, d2);
    const F3 n2 = f3cross(d2, d3);
    const float inv = 1.0f / (sqrtf(f3dot(d2, d2)) + 1e-12f);
    const F3 b2n = {d2.x * inv, d2.y * inv, d2.z * inv};
    const F3 m1  = f3cross(n1, b2n);
    const float ang = atan2f(f3dot(m1, n2), f3dot(n1, n2));

    // ---- partner exchange through LDS (sentinel 1e30 = torsion invalid) ----
    s_ang[b * 2 + t] = ok4 ? ang : 1e30f;
    __syncthreads();
    const float2 pp  = ((const float2*)s_ang)[b];   // ds_read_b64, conflict-free
    const float  phi = pp.x, psi = pp.y;
    const bool   okb = fabsf(phi) < 1e29f && fabsf(psi) < 1e29f;

    // ---- neighbor-dependent table selection (tiny L1-resident tables) ----
    const int  uc   = bt_upper_conn[bt];
    const int  nb   = s_inter[(b * NCn + uc) * 2 + 0];
    const bool nbok = nb >= 0;
    const int  nbc  = nb > 0 ? nb : 0;
    const int  tab  = bt_rama_table[bt * 2 + bt_is_pro[s_bt[nbc]]];

    float e = 0.0f;
    if (okb && nbok) {
        const float4 tp4 = ((const float4*)table_params)[tab]; // start.xy, step.xy
        float wphi[4], wpsi[4];
        int   ii[4], jj[4];
        #pragma unroll
        for (int d = 0; d < 2; ++d) {
            const float a0    = (d == 0) ? phi   : psi;
            const float start = (d == 0) ? tp4.x : tp4.y;
            const float step  = (d == 0) ? tp4.z : tp4.w;
            const float u   = (a0 - start) / step;
            const float i0f = floorf(u);
            const float f   = u - i0f;
            const float f2 = f * f, f3v = f2 * f;
            float* w = (d == 0) ? wphi : wpsi;
            w[0] = 0.5f * (-f3v + 2.0f * f2 - f);
            w[1] = 0.5f * (3.0f * f3v - 5.0f * f2 + 2.0f);
            w[2] = 0.5f * (-3.0f * f3v + 4.0f * f2 + f);
            w[3] = 0.5f * (f3v - f2);
            // one modulo + increment-with-wrap (replaces 4 magic-mul mods)
            int m = ((int)i0f - 1) % NG;
            if (m < 0) m += NG;
            int* idx = (d == 0) ? ii : jj;
            idx[0] = m;
            #pragma unroll
            for (int k = 1; k < 4; ++k) {
                m = (m + 1 == NG) ? 0 : m + 1;
                idx[k] = m;
            }
        }
        // rows {0,1} for t=0, rows {2,3} for t=1 — explicit selects keep all
        // array indices compile-time constant (no scratch, rule #20)
        const int   ra = t ? ii[2]   : ii[0];
        const int   rb = t ? ii[3]   : ii[1];
        const float wa = t ? wphi[2] : wphi[0];
        const float wb = t ? wphi[3] : wphi[1];
        const float* T  = rama_tables + (size_t)tab * NG * NG;
        const float* Ta = T + ra * NG;
        const float* Tb = T + rb * NG;
        float sa = 0.0f, sb = 0.0f;
        #pragma unroll
        for (int j = 0; j < 4; ++j) {
            sa += wpsi[j] * Ta[jj[j]];
            sb += wpsi[j] * Tb[jj[j]];
        }
        e = wa * sa + wb * sb;
    }

    // ---- block-wide reduction ----
    float v = e;
    #pragma unroll
    for (int o = 32; o > 0; o >>= 1) v += __shfl_down(v, o);
    const int wave = tid >> 6;
    const int lane = tid & 63;
    if (lane == 0) partial[wave] = v;
    __syncthreads();
    if (tid == 0) {
        float s = 0.0f;
        #pragma unroll
        for (int i = 0; i < NTHREADS / 64; ++i) s += partial[i];
        out[p] = s;
    }
}

extern "C" void kernel_launch(void* const* d_in, const int* in_sizes, int n_in,
                              void* d_out, int out_size, void* d_ws, size_t ws_size,
                              hipStream_t stream) {
    (void)in_sizes; (void)n_in; (void)out_size; (void)d_ws; (void)ws_size;
    rama_kernel<<<NP, NTHREADS, 0, stream>>>(
        (const float*)d_in[0],   // coords
        (const int*)d_in[1],     // pose_stack_block_coord_offset
        (const int*)d_in[2],     // pose_stack_block_type
        (const int*)d_in[3],     // pose_stack_inter_residue_connections
        (const int*)d_in[4],     // bt_atom_downstream_of_conn
        (const int*)d_in[5],     // bt_rama_table
        (const int*)d_in[6],     // bt_upper_conn_ind
        (const int*)d_in[7],     // bt_is_pro
        (const int*)d_in[8],     // bt_rama_torsion_atoms
        (const float*)d_in[9],   // rama_tables
        (const float*)d_in[10],  // table_params
        (float*)d_out);
}

// Round 2
// 175.518 us; speedup vs baseline: 1.0121x; 1.0121x over previous
//
#include <hip/hip_runtime.h>
#include <math.h>

#define NP 512
#define NBLK 512
#define NTHREADS 1024
#define NA_ 32
#define NCn 3
#define NG 36
#define NBT 40
#define NTAB 40

struct F3 { float x, y, z; };
__device__ inline F3 f3sub(F3 a, F3 b) { return {a.x - b.x, a.y - b.y, a.z - b.z}; }
__device__ inline F3 f3cross(F3 a, F3 b) {
    return {a.y * b.z - a.z * b.y, a.z * b.x - a.x * b.z, a.x * b.y - a.y * b.x};
}
__device__ inline float f3dot(F3 a, F3 b) { return a.x * b.x + a.y * b.y + a.z * b.z; }

// SINGLE-VARIABLE CHANGE vs round 1: __launch_bounds__(1024, 8) -> (1024, 4).
// The 8-waves/EU bound forced VGPR<=64, which this body cannot fit -> scratch
// spills on the dependent chain (the hypothesized reason the kernel runs ~110us
// vs a ~10us work floor). Cap 128 VGPRs, 16 waves/CU, zero spill.
__global__ __launch_bounds__(NTHREADS, 4) void rama_kernel(
    const float* __restrict__ coords,        // (P, NB*NA, 3)
    const int*   __restrict__ offsets,       // (P, NB)
    const int*   __restrict__ block_type,    // (P, NB)
    const int*   __restrict__ inter,         // (P, NB, NC, 2)
    const int*   __restrict__ down,          // (NBT, NC, NA)
    const int*   __restrict__ bt_rama_table, // (NBT, 2)
    const int*   __restrict__ bt_upper_conn, // (NBT,)
    const int*   __restrict__ bt_is_pro,     // (NBT,)
    const int*   __restrict__ tor_atoms,     // (NBT, 8, 3)
    const float* __restrict__ rama_tables,   // (NTAB, G, G)
    const float* __restrict__ table_params,  // (NTAB, 2, 2)
    float*       __restrict__ out)           // (P,)
{
    __shared__ __align__(16) int   s_bt[NBLK];
    __shared__ __align__(16) int   s_off[NBLK];
    __shared__ __align__(16) int   s_inter[NBLK * NCn * 2];
    __shared__ __align__(16) float s_ang[NBLK * 2];
    __shared__ float partial[NTHREADS / 64];

    const int p   = blockIdx.x;
    const int tid = threadIdx.x;

    // ---- per-pose metadata (16 KB = 4096 ints = 1024 int4): one int4
    //      load + one ds_write_b128 per thread, fully coalesced ----
    {
        const int4* gi = (const int4*)(inter      + (size_t)p * NBLK * NCn * 2);
        const int4* gb = (const int4*)(block_type + (size_t)p * NBLK);
        const int4* go = (const int4*)(offsets    + (size_t)p * NBLK);
        if (tid < 768)      ((int4*)s_inter)[tid]     = gi[tid];
        else if (tid < 896) ((int4*)s_bt)[tid - 768]  = gb[tid - 768];
        else                ((int4*)s_off)[tid - 896] = go[tid - 896];
    }
    __syncthreads();

    const int b = tid & (NBLK - 1);   // residue
    const int t = tid >> 9;           // torsion (wave-uniform)
    const int bt    = s_bt[b];
    const int off_b = s_off[b];
    const float* pose_coords = coords + (size_t)p * NBLK * NA_ * 3;

    // ---- 12 tor ints for this (bt, torsion): contiguous, 48B-aligned ->
    //      3x dwordx4 straight from the L1-resident 3.75 KB table ----
    const int4* tq = (const int4*)tor_atoms + (6 * bt + 3 * t);
    const int4 w0 = tq[0], w1 = tq[1], w2 = tq[2];
    const int ai[4]  = {w0.x, w0.w, w1.z, w2.y};
    const int ci[4]  = {w0.y, w1.x, w1.w, w2.z};
    const int nbd[4] = {w0.z, w1.y, w2.x, w2.w};

    // ---- resolve 4 atom indices ----
    int  g[4];
    bool ok4 = true;
    #pragma unroll
    for (int a = 0; a < 4; ++a) {
        if (ai[a] >= 0) {
            g[a] = off_b + ai[a];
        } else {
            const int sc = ci[a] > 0 ? ci[a] : 0;
            const int ib = (b * NCn + sc) * 2;
            const int ob = s_inter[ib + 0];
            const int oc = s_inter[ib + 1];
            ok4 = ok4 && (ci[a] >= 0) && (ob >= 0);
            const int obc = ob > 0 ? ob : 0;
            const int occ = oc > 0 ? oc : 0;
            const int obt = s_bt[obc];
            g[a] = s_off[obc] + down[(obt * NCn + occ) * NA_ + nbd[a]];
        }
    }

    // ---- coord gather: vector fast path for a contiguous aligned triple ----
    F3 pts[4];
    bool done = false;
    if (g[2] == g[1] + 1 && g[3] == g[2] + 1 && (g[1] & 3) == 0) {
        const float* base = pose_coords + (size_t)g[1] * 3;
        const float4 q0 = ((const float4*)base)[0];
        const float4 q1 = ((const float4*)base)[1];
        const float  q2 = base[8];
        pts[1] = {q0.x, q0.y, q0.z};
        pts[2] = {q0.w, q1.x, q1.y};
        pts[3] = {q1.z, q1.w, q2};
        const float* c0 = pose_coords + (size_t)g[0] * 3;
        pts[0] = {c0[0], c0[1], c0[2]};
        done = true;
    } else if (g[1] == g[0] + 1 && g[2] == g[1] + 1 && (g[0] & 3) == 0) {
        const float* base = pose_coords + (size_t)g[0] * 3;
        const float4 q0 = ((const float4*)base)[0];
        const float4 q1 = ((const float4*)base)[1];
        const float  q2 = base[8];
        pts[0] = {q0.x, q0.y, q0.z};
        pts[1] = {q0.w, q1.x, q1.y};
        pts[2] = {q1.z, q1.w, q2};
        const float* c3 = pose_coords + (size_t)g[3] * 3;
        pts[3] = {c3[0], c3[1], c3[2]};
        done = true;
    }
    if (!done) {
        #pragma unroll
        for (int a = 0; a < 4; ++a) {
            const float* c = pose_coords + (size_t)g[a] * 3;
            pts[a] = {c[0], c[1], c[2]};
        }
    }

    // ---- dihedral ----
    const F3 d1 = f3sub(pts[1], pts[0]);
    const F3 d2 = f3sub(pts[2], pts[1]);
    const F3 d3 = f3sub(pts[3], pts[2]);
    const F3 n1 = f3cross(d1, d2);
    const F3 n2 = f3cross(d2, d3);
    const float inv = 1.0f / (sqrtf(f3dot(d2, d2)) + 1e-12f);
    const F3 b2n = {d2.x * inv, d2.y * inv, d2.z * inv};
    const F3 m1  = f3cross(n1, b2n);
    const float ang = atan2f(f3dot(m1, n2), f3dot(n1, n2));

    // ---- partner exchange through LDS (sentinel 1e30 = torsion invalid) ----
    s_ang[b * 2 + t] = ok4 ? ang : 1e30f;
    __syncthreads();
    const float2 pp  = ((const float2*)s_ang)[b];   // ds_read_b64, conflict-free
    const float  phi = pp.x, psi = pp.y;
    const bool   okb = fabsf(phi) < 1e29f && fabsf(psi) < 1e29f;

    // ---- neighbor-dependent table selection (tiny L1-resident tables) ----
    const int  uc   = bt_upper_conn[bt];
    const int  nb   = s_inter[(b * NCn + uc) * 2 + 0];
    const bool nbok = nb >= 0;
    const int  nbc  = nb > 0 ? nb : 0;
    const int  tab  = bt_rama_table[bt * 2 + bt_is_pro[s_bt[nbc]]];

    float e = 0.0f;
    if (okb && nbok) {
        const float4 tp4 = ((const float4*)table_params)[tab]; // start.xy, step.xy
        float wphi[4], wpsi[4];
        int   ii[4], jj[4];
        #pragma unroll
        for (int d = 0; d < 2; ++d) {
            const float a0    = (d == 0) ? phi   : psi;
            const float start = (d == 0) ? tp4.x : tp4.y;
            const float step  = (d == 0) ? tp4.z : tp4.w;
            const float u   = (a0 - start) / step;
            const float i0f = floorf(u);
            const float f   = u - i0f;
            const float f2 = f * f, f3v = f2 * f;
            float* w = (d == 0) ? wphi : wpsi;
            w[0] = 0.5f * (-f3v + 2.0f * f2 - f);
            w[1] = 0.5f * (3.0f * f3v - 5.0f * f2 + 2.0f);
            w[2] = 0.5f * (-3.0f * f3v + 4.0f * f2 + f);
            w[3] = 0.5f * (f3v - f2);
            int m = ((int)i0f - 1) % NG;
            if (m < 0) m += NG;
            int* idx = (d == 0) ? ii : jj;
            idx[0] = m;
            #pragma unroll
            for (int k = 1; k < 4; ++k) {
                m = (m + 1 == NG) ? 0 : m + 1;
                idx[k] = m;
            }
        }
        const int   ra = t ? ii[2]   : ii[0];
        const int   rb = t ? ii[3]   : ii[1];
        const float wa = t ? wphi[2] : wphi[0];
        const float wb = t ? wphi[3] : wphi[1];
        const float* T  = rama_tables + (size_t)tab * NG * NG;
        const float* Ta = T + ra * NG;
        const float* Tb = T + rb * NG;
        float sa = 0.0f, sb = 0.0f;
        #pragma unroll
        for (int j = 0; j < 4; ++j) {
            sa += wpsi[j] * Ta[jj[j]];
            sb += wpsi[j] * Tb[jj[j]];
        }
        e = wa * sa + wb * sb;
    }

    // ---- block-wide reduction ----
    float v = e;
    #pragma unroll
    for (int o = 32; o > 0; o >>= 1) v += __shfl_down(v, o);
    const int wave = tid >> 6;
    const int lane = tid & 63;
    if (lane == 0) partial[wave] = v;
    __syncthreads();
    if (tid == 0) {
        float s = 0.0f;
        #pragma unroll
        for (int i = 0; i < NTHREADS / 64; ++i) s += partial[i];
        out[p] = s;
    }
}

extern "C" void kernel_launch(void* const* d_in, const int* in_sizes, int n_in,
                              void* d_out, int out_size, void* d_ws, size_t ws_size,
                              hipStream_t stream) {
    (void)in_sizes; (void)n_in; (void)out_size; (void)d_ws; (void)ws_size;
    rama_kernel<<<NP, NTHREADS, 0, stream>>>(
        (const float*)d_in[0],   // coords
        (const int*)d_in[1],     // pose_stack_block_coord_offset
        (const int*)d_in[2],     // pose_stack_block_type
        (const int*)d_in[3],     // pose_stack_inter_residue_connections
        (const int*)d_in[4],     // bt_atom_downstream_of_conn
        (const int*)d_in[5],     // bt_rama_table
        (const int*)d_in[6],     // bt_upper_conn_ind
        (const int*)d_in[7],     // bt_is_pro
        (const int*)d_in[8],     // bt_rama_torsion_atoms
        (const float*)d_in[9],   // rama_tables
        (const float*)d_in[10],  // table_params
        (float*)d_out);
}

// Round 3
// 173.475 us; speedup vs baseline: 1.0241x; 1.0118x over previous
//
#include <hip/hip_runtime.h>
#include <math.h>

#define NP 512
#define NBLK 512
#define NT 512
#define NA_ 32
#define NCn 3
#define NG 36

struct F3 { float x, y, z; };
__device__ inline F3 f3sub(F3 a, F3 b) { return {a.x - b.x, a.y - b.y, a.z - b.z}; }
__device__ inline F3 f3cross(F3 a, F3 b) {
    return {a.y * b.z - a.z * b.y, a.z * b.x - a.x * b.z, a.x * b.y - a.y * b.x};
}
__device__ inline float f3dot(F3 a, F3 b) { return a.x * b.x + a.y * b.y + a.z * b.z; }

// max err ~3e-7 rad; replaces the ~100-inst ocml atan2 libcall on the
// dependent chain. Guarded against 0/0.
__device__ inline float fast_atan2(float y, float x) {
    const float ax = fabsf(x), ay = fabsf(y);
    const float mx = fmaxf(ax, ay), mn = fminf(ax, ay);
    const float r  = mn * __builtin_amdgcn_rcpf(fmaxf(mx, 1e-37f));
    const float s  = r * r;
    float p = -0.0117212f;
    p = fmaf(p, s,  0.05265332f);
    p = fmaf(p, s, -0.11643287f);
    p = fmaf(p, s,  0.19354346f);
    p = fmaf(p, s, -0.33262347f);
    p = fmaf(p, s,  0.99997726f);
    p = p * r;
    p = (ay > ax) ? (1.5707963267948966f - p) : p;
    p = (x < 0.0f) ? (3.14159265358979323f - p) : p;
    return copysignf(p, y);
}

__device__ inline float dihedral4(F3 p0, F3 p1, F3 p2, F3 p3) {
    const F3 b1 = f3sub(p1, p0);
    const F3 b2 = f3sub(p2, p1);
    const F3 b3 = f3sub(p3, p2);
    const F3 n1 = f3cross(b1, b2);
    const F3 n2 = f3cross(b2, b3);
    const float i2 = __builtin_amdgcn_rsqf(f3dot(b2, b2) + 1e-24f);
    return fast_atan2(i2 * f3dot(f3cross(n1, b2), n2), f3dot(n1, n2));
}

// One thread per residue computes BOTH torsions (phi/psi share 3 atoms and two
// bonds: phi's n2 == psi's n1). No LDS metadata staging, no partner-exchange
// barrier -- waves run fully independently until the 8-wave final reduction.
// The kernel's work floor is ~5-10us; everything above that was barrier/latency
// structure, which this version removes.
__global__ __launch_bounds__(NT, 4) void rama_kernel(
    const float* __restrict__ coords,        // (P, NB*NA, 3)
    const int*   __restrict__ offsets,       // (P, NB)
    const int*   __restrict__ block_type,    // (P, NB)
    const int*   __restrict__ inter,         // (P, NB, NC, 2)
    const int*   __restrict__ down,          // (NBT, NC, NA)
    const int*   __restrict__ bt_rama_table, // (NBT, 2)
    const int*   __restrict__ bt_upper_conn, // (NBT,)
    const int*   __restrict__ bt_is_pro,     // (NBT,)
    const int*   __restrict__ tor_atoms,     // (NBT, 8, 3)
    const float* __restrict__ rama_tables,   // (NTAB, G, G)
    const float* __restrict__ table_params,  // (NTAB, 2, 2)
    float*       __restrict__ out)           // (P,)
{
    __shared__ float partial[NT / 64];

    const int p  = blockIdx.x;
    const int b  = threadIdx.x;
    const int pb = p * NBLK + b;

    const int bt    = block_type[pb];   // coalesced
    const int off_b = offsets[pb];      // coalesced
    const float* pose_coords = coords + (size_t)p * NBLK * NA_ * 3;
    const int*   inter_p     = inter  + (size_t)p * NBLK * NCn * 2;

    // ---- all 8 torsion-atom descriptors: 6x int4 from the 3.75KB L1 table ----
    const int4* tq = (const int4*)tor_atoms + 6 * bt;
    const int4 w0 = tq[0], w1 = tq[1], w2 = tq[2], w3 = tq[3], w4 = tq[4], w5 = tq[5];
    const int ai[8]  = {w0.x, w0.w, w1.z, w2.y,  w3.x, w3.w, w4.z, w5.y};
    const int ci[8]  = {w0.y, w1.x, w1.w, w2.z,  w3.y, w4.x, w4.w, w5.z};
    const int nbd[8] = {w0.z, w1.y, w2.x, w2.w,  w3.z, w4.y, w5.x, w5.w};

    // ---- resolve 8 global atom indices (phi: 0..3, psi: 4..7) ----
    int  g[8];
    bool ok_phi = true, ok_psi = true;
    #pragma unroll
    for (int e = 0; e < 8; ++e) {
        if (ai[e] >= 0) {
            g[e] = off_b + ai[e];
        } else {
            const int sc = ci[e] > 0 ? ci[e] : 0;
            const int ob = inter_p[(b * NCn + sc) * 2 + 0];
            const int oc = inter_p[(b * NCn + sc) * 2 + 1];
            const bool okc = (ci[e] >= 0) && (ob >= 0);
            if (e < 4) ok_phi = ok_phi && okc; else ok_psi = ok_psi && okc;
            const int obc = ob > 0 ? ob : 0;
            const int occ = oc > 0 ? oc : 0;
            const int obt = block_type[p * NBLK + obc];   // L1 (neighbor line)
            g[e] = offsets[p * NBLK + obc] + down[(obt * NCn + occ) * NA_ + nbd[e]];
        }
    }

    // ---- coords + both dihedrals; fast path exploits the shared middle
    //      triple (phi atoms 1..3 == psi atoms 0..2, contiguous, aligned) ----
    float phi, psi;
    const bool sh = (g[1] == g[4]) && (g[2] == g[5]) && (g[3] == g[6]);
    if (sh && g[2] == g[1] + 1 && g[3] == g[1] + 2 && ((g[1] & 3) == 0)) {
        const float* base = pose_coords + (size_t)g[1] * 3;
        const float4 q0 = ((const float4*)base)[0];
        const float4 q1 = ((const float4*)base)[1];
        const float  f8 = base[8];
        const F3 P1 = {q0.x, q0.y, q0.z};
        const F3 P2 = {q0.w, q1.x, q1.y};
        const F3 P3 = {q1.z, q1.w, f8};
        const float* c0 = pose_coords + (size_t)g[0] * 3;
        const float* c7 = pose_coords + (size_t)g[7] * 3;
        const F3 P0 = {c0[0], c0[1], c0[2]};
        const F3 P4 = {c7[0], c7[1], c7[2]};
        const F3 b1 = f3sub(P1, P0);
        const F3 b2 = f3sub(P2, P1);
        const F3 b3 = f3sub(P3, P2);
        const F3 b4 = f3sub(P4, P3);
        const F3 n1 = f3cross(b1, b2);
        const F3 n2 = f3cross(b2, b3);   // shared: phi's n2 == psi's n1
        const F3 n3 = f3cross(b3, b4);
        const float i2 = __builtin_amdgcn_rsqf(f3dot(b2, b2) + 1e-24f);
        const float i3 = __builtin_amdgcn_rsqf(f3dot(b3, b3) + 1e-24f);
        phi = fast_atan2(i2 * f3dot(f3cross(n1, b2), n2), f3dot(n1, n2));
        psi = fast_atan2(i3 * f3dot(f3cross(n2, b3), n3), f3dot(n2, n3));
    } else {
        // generic fallback (exec-masked off when no lane needs it)
        F3 q[8];
        #pragma unroll
        for (int e = 0; e < 8; ++e) {
            const float* c = pose_coords + (size_t)g[e] * 3;
            q[e] = {c[0], c[1], c[2]};
        }
        phi = dihedral4(q[0], q[1], q[2], q[3]);
        psi = dihedral4(q[4], q[5], q[6], q[7]);
    }

    // ---- neighbor-dependent table selection (L1-resident tiny tables) ----
    const int  uc   = bt_upper_conn[bt];
    const int  nb   = inter_p[(b * NCn + uc) * 2 + 0];
    const bool nbok = nb >= 0;
    const int  nbc  = nb > 0 ? nb : 0;
    const int  tab  = bt_rama_table[bt * 2 + bt_is_pro[block_type[p * NBLK + nbc]]];

    float e = 0.0f;
    if (ok_phi && ok_psi && nbok) {
        const float4 tp4 = ((const float4*)table_params)[tab]; // {start_phi,start_psi,step_phi,step_psi}
        float wphi[4], wpsi[4];
        int   ii[4], jj[4];
        #pragma unroll
        for (int d = 0; d < 2; ++d) {
            const float a0    = (d == 0) ? phi   : psi;
            const float start = (d == 0) ? tp4.x : tp4.y;
            const float step  = (d == 0) ? tp4.z : tp4.w;
            const float u   = (a0 - start) / step;
            const float i0f = floorf(u);
            const float f   = u - i0f;
            const float f2 = f * f, f3v = f2 * f;
            float* w = (d == 0) ? wphi : wpsi;
            w[0] = 0.5f * (-f3v + 2.0f * f2 - f);
            w[1] = 0.5f * (3.0f * f3v - 5.0f * f2 + 2.0f);
            w[2] = 0.5f * (-3.0f * f3v + 4.0f * f2 + f);
            w[3] = 0.5f * (f3v - f2);
            int m = ((int)i0f - 1) % NG;
            if (m < 0) m += NG;
            int* idx = (d == 0) ? ii : jj;
            idx[0] = m;
            #pragma unroll
            for (int k = 1; k < 4; ++k) {
                m = (m + 1 == NG) ? 0 : m + 1;
                idx[k] = m;
            }
        }
        const float* T = rama_tables + (size_t)tab * NG * NG;
        #pragma unroll
        for (int i = 0; i < 4; ++i) {
            const float* Tr = T + ii[i] * NG;
            float rs = 0.0f;
            #pragma unroll
            for (int j = 0; j < 4; ++j) rs += wpsi[j] * Tr[jj[j]];
            e += wphi[i] * rs;
        }
    }

    // ---- block reduction: wave shuffle -> 8 partials -> thread 0 ----
    float v = e;
    #pragma unroll
    for (int o = 32; o > 0; o >>= 1) v += __shfl_down(v, o);
    const int wave = threadIdx.x >> 6;
    const int lane = threadIdx.x & 63;
    if (lane == 0) partial[wave] = v;
    __syncthreads();
    if (threadIdx.x == 0) {
        float s = 0.0f;
        #pragma unroll
        for (int i = 0; i < NT / 64; ++i) s += partial[i];
        out[p] = s;
    }
}

extern "C" void kernel_launch(void* const* d_in, const int* in_sizes, int n_in,
                              void* d_out, int out_size, void* d_ws, size_t ws_size,
                              hipStream_t stream) {
    (void)in_sizes; (void)n_in; (void)out_size; (void)d_ws; (void)ws_size;
    rama_kernel<<<NP, NT, 0, stream>>>(
        (const float*)d_in[0],   // coords
        (const int*)d_in[1],     // pose_stack_block_coord_offset
        (const int*)d_in[2],     // pose_stack_block_type
        (const int*)d_in[3],     // pose_stack_inter_residue_connections
        (const int*)d_in[4],     // bt_atom_downstream_of_conn
        (const int*)d_in[5],     // bt_rama_table
        (const int*)d_in[6],     // bt_upper_conn_ind
        (const int*)d_in[7],     // bt_is_pro
        (const int*)d_in[8],     // bt_rama_torsion_atoms
        (const float*)d_in[9],   // rama_tables
        (const float*)d_in[10],  // table_params
        (float*)d_out);
}